// Round 1
// baseline (345.272 us; speedup 1.0000x reference)
//
#include <hip/hip_runtime.h>

#define BHX   32      // B*H
#define NSEQ  8192
#define NMASK 8191
#define DIM   64
#define NPROJ 7
#define NBUCK 128
#define NBLK  32      // key blocks of 256
#define QBS   256
#define SSIZE 256
#define LOG32 3.4657359027997265f
#define KPAD  72      // padded leading dim (bf16 units)

typedef unsigned short u16;
typedef unsigned int   u32;
typedef unsigned char  u8;
typedef __attribute__((ext_vector_type(8))) short bf16x8;
typedef __attribute__((ext_vector_type(4))) float f32x4;

union B8U { u32 u[4]; bf16x8 v; };

__device__ __forceinline__ u16 f2bf(float f){
    u32 u = __float_as_uint(f);
    u32 r = u + 0x7fffu + ((u >> 16) & 1u);   // RNE
    return (u16)(r >> 16);
}
__device__ __forceinline__ u32 pk2(float a, float b){
    return (u32)f2bf(a) | ((u32)f2bf(b) << 16);
}
__device__ __forceinline__ f32x4 mfma16(bf16x8 a, bf16x8 b, f32x4 c){
    return __builtin_amdgcn_mfma_f32_16x16x32_bf16(a, b, c, 0, 0, 0);
}

// ---------------------------------------------------------------------------
// Kernel 1a: LSH hash. grid (8 slabs, BHX, 2 tensors), 256 thr, 4 rows/thr.
// proj read as float4 from LDS (112 ds_read_b128/row vs 448 ds_read_b32).
// Per-dot[r] accumulation order unchanged (d ascending) -> identical signs.
// ---------------------------------------------------------------------------
__global__ __launch_bounds__(256) void hash_kernel(
    const float* __restrict__ qg, const float* __restrict__ kg,
    const float* __restrict__ projg,
    u8* __restrict__ bkt)
{
    const int slab = blockIdx.x, bh = blockIdx.y, tz = blockIdx.z;
    const float* __restrict__ x = tz ? kg : qg;
    u8* __restrict__ ob = bkt + ((size_t)tz * BHX + bh) * NSEQ;

    __shared__ float projs[NPROJ][DIM];   // rows 256 B aligned -> float4 reads
    const int t = threadIdx.x;
    if (t < 112) {
        #pragma unroll
        for (int u = 0; u < 4; u++) {
            int e = t * 4 + u;
            projs[e % NPROJ][e / NPROJ] = projg[e];
        }
    }
    __syncthreads();

    const size_t bhN = (size_t)bh * NSEQ;
    #pragma unroll
    for (int j = 0; j < 4; j++) {
        int n = slab * 1024 + j * 256 + t;
        const float4* row = (const float4*)(x + (bhN + n) * DIM);
        float dot[NPROJ];
        #pragma unroll
        for (int r = 0; r < NPROJ; r++) dot[r] = 0.0f;
        #pragma unroll
        for (int c = 0; c < 16; c++) {
            float4 wv = row[c];
            #pragma unroll
            for (int r = 0; r < NPROJ; r++) {
                float4 p = *(const float4*)&projs[r][c * 4];
                dot[r] += wv.x * p.x;
                dot[r] += wv.y * p.y;
                dot[r] += wv.z * p.z;
                dot[r] += wv.w * p.w;
            }
        }
        int code = 0;
        #pragma unroll
        for (int r = 0; r < NPROJ; r++) code |= (dot[r] > 0.0f ? 1 : 0) << r;
        ob[n] = (u8)(code ^ (code >> 1));
    }
}

// ---------------------------------------------------------------------------
// Kernel 1b: stable counting sort per (tensor, head). grid (BHX, 2), 256 thr.
// (unchanged this round — isolate attn/hash delta)
// ---------------------------------------------------------------------------
__global__ __launch_bounds__(256) void sort_kernel(
    const u8* __restrict__ bkt,
    u16* __restrict__ qidx, u16* __restrict__ kidx)
{
    const int bh = blockIdx.x, tz = blockIdx.y;
    const u8* __restrict__ ib = bkt + ((size_t)tz * BHX + bh) * NSEQ;
    u16* __restrict__ idx = (tz ? kidx : qidx) + (size_t)bh * NSEQ;

    __shared__ u8  lb[NSEQ];            // 8 KB
    __shared__ u16 hist[NBUCK][258];    // 66 KB, +2 pad
    __shared__ int base[NBUCK];
    __shared__ int tot[NBUCK];

    const int t = threadIdx.x;
    {
        const uint4* src = (const uint4*)ib;
        uint4* dst = (uint4*)lb;
        dst[t] = src[t];
        dst[256 + t] = src[256 + t];
    }
    u32* hz = (u32*)&hist[0][0];
    for (int z = t; z < (NBUCK * 258) / 2; z += 256) hz[z] = 0u;
    __syncthreads();

    #pragma unroll 4
    for (int i = 0; i < 32; i++) hist[lb[t * 32 + i]][t]++;
    __syncthreads();

    if (t < NBUCK) {
        u32 run = 0;
        for (int c = 0; c < 256; c++) {
            u32 v = hist[t][c];
            hist[t][c] = (u16)run;
            run += v;
        }
        tot[t] = (int)run;
    }
    __syncthreads();
    if (t == 0) {
        int run = 0;
        for (int b = 0; b < NBUCK; b++) { base[b] = run; run += tot[b]; }
    }
    __syncthreads();

    #pragma unroll 4
    for (int i = 0; i < 32; i++) {
        int n = t * 32 + i;
        int b = lb[n];
        int pos = base[b] + hist[b][t];
        hist[b][t]++;
        idx[pos] = (u16)n;
    }
}

// ---------------------------------------------------------------------------
// Kernel 2: MFMA flash attention over 512 keys (256 block-diag + 256 sampled).
// v2: 512 thr = 8 waves; wave owns 32 sorted queries (O = 32 regs -> combined
// regfile <= 128/wave -> 4 waves/SIMD -> 16 waves/CU, 2x prior occupancy).
// Staging split: waves 0-3 stage K, waves 4-7 stage V^T (shorter dep chains).
// Vt 16B-chunk XOR swizzle (chunk ^= d>>4): transpose-write 8-way -> 4-way.
// ---------------------------------------------------------------------------
__global__ __launch_bounds__(512, 4) void attn_mfma(
    const float* __restrict__ qg, const float* __restrict__ kg,
    const float* __restrict__ vg,
    const u16* __restrict__ qidx, const u16* __restrict__ kidx,
    const int* __restrict__ samp,
    float* __restrict__ outg)
{
    __shared__ u16  Ks[64 * KPAD];        // [key][d]           9.2 KB
    __shared__ u16  Vt[64 * KPAD];        // [d][key] swizzled  9.2 KB
    __shared__ u16  Ps[256 * KPAD];       // [query][key]      36.9 KB
    __shared__ float addv[64];

    const int qb = blockIdx.x, bh = blockIdx.y, t = threadIdx.x;
    const int w = t >> 6, lane = t & 63, c = lane & 15, g = lane >> 4;
    const size_t bhN = (size_t)bh * NSEQ;

    // ---- load my wave's 32 query rows as B-fragments (scale folded in) ----
    int qi[2];
    bf16x8 qf[2][2];
    #pragma unroll
    for (int qt = 0; qt < 2; qt++) {
        qi[qt] = ((int)qidx[bhN + qb * QBS + w * 32 + qt * 16 + c]) & NMASK;
        const float* qr = qg + (bhN + (size_t)qi[qt]) * DIM;
        #pragma unroll
        for (int dk = 0; dk < 2; dk++) {
            int d0 = dk * 32 + g * 8;
            float4 xx = *(const float4*)(qr + d0);
            float4 yy = *(const float4*)(qr + d0 + 4);
            B8U f;
            f.u[0] = pk2(xx.x * 0.125f, xx.y * 0.125f);
            f.u[1] = pk2(xx.z * 0.125f, xx.w * 0.125f);
            f.u[2] = pk2(yy.x * 0.125f, yy.y * 0.125f);
            f.u[3] = pk2(yy.z * 0.125f, yy.w * 0.125f);
            qf[qt][dk] = f.v;
        }
    }

    f32x4 O[4][2];   // [dt][qt], C layout: row=d, col=query
    #pragma unroll
    for (int dt = 0; dt < 4; dt++)
        #pragma unroll
        for (int qt = 0; qt < 2; qt++) O[dt][qt] = (f32x4)0.0f;
    float m[2] = {-1e30f, -1e30f};
    float l[2] = {0.0f, 0.0f};

    for (int cc = 0; cc < 8; cc++) {
        __syncthreads();
        // ---- stage 64 keys: waves 0-3 -> K [key][d]; waves 4-7 -> V^T ----
        {
            const int half = t >> 8;          // 0: K, 1: V
            const int tt = t & 255;
            const int s = tt >> 2, seg = (tt & 3) * 16;
            int grow; float add;
            if (cc < 4) {
                grow = ((int)kidx[bhN + qb * QBS + cc * 64 + s]) & NMASK;
                add  = 0.0f;
            } else {
                int sidx = samp[bh * SSIZE + (cc - 4) * 64 + s] & NMASK;
                grow = ((int)kidx[bhN + sidx]) & NMASK;
                add  = ((sidx >> 8) == qb) ? -1e30f : LOG32;
            }
            if (half == 0) {
                const float4* kr = (const float4*)(kg + (bhN + (size_t)grow) * DIM + seg);
                float4 a = kr[0], b = kr[1], e = kr[2], d = kr[3];
                u32* dst = (u32*)&Ks[s * KPAD + seg];
                dst[0] = pk2(a.x, a.y); dst[1] = pk2(a.z, a.w);
                dst[2] = pk2(b.x, b.y); dst[3] = pk2(b.z, b.w);
                dst[4] = pk2(e.x, e.y); dst[5] = pk2(e.z, e.w);
                dst[6] = pk2(d.x, d.y); dst[7] = pk2(d.z, d.w);
                if ((tt & 3) == 0) addv[s] = add;
            } else {
                const float4* vr = (const float4*)(vg + (bhN + (size_t)grow) * DIM + seg);
                float4 va = vr[0], vb = vr[1], ve = vr[2], vd = vr[3];
                float vv[16] = {va.x, va.y, va.z, va.w, vb.x, vb.y, vb.z, vb.w,
                                ve.x, ve.y, ve.z, ve.w, vd.x, vd.y, vd.z, vd.w};
                // swizzled column: chunk(=s>>3) ^ (d>>4), d>>4 == (tt&3)
                const int col = (((s >> 3) ^ (tt & 3)) << 3) | (s & 7);
                #pragma unroll
                for (int i = 0; i < 16; i++)
                    Vt[(seg + i) * KPAD + col] = f2bf(vv[i]);
            }
        }
        __syncthreads();

        bf16x8 ka[4][2];
        #pragma unroll
        for (int kt = 0; kt < 4; kt++)
            #pragma unroll
            for (int dk = 0; dk < 2; dk++)
                ka[kt][dk] = *(const bf16x8*)&Ks[(kt * 16 + c) * KPAD + dk * 32 + g * 8];

        #pragma unroll
        for (int qt = 0; qt < 2; qt++) {
            f32x4 S[4];
            #pragma unroll
            for (int kt = 0; kt < 4; kt++) {
                S[kt] = (f32x4)0.0f;
                S[kt] = mfma16(ka[kt][0], qf[qt][0], S[kt]);
                S[kt] = mfma16(ka[kt][1], qf[qt][1], S[kt]);
                S[kt] += *(const f32x4*)&addv[kt * 16 + g * 4];  // fold bias early
            }
            float cmax = -1e30f;
            #pragma unroll
            for (int kt = 0; kt < 4; kt++)
                #pragma unroll
                for (int r = 0; r < 4; r++)
                    cmax = fmaxf(cmax, S[kt][r]);
            cmax = fmaxf(cmax, __shfl_xor(cmax, 16));
            cmax = fmaxf(cmax, __shfl_xor(cmax, 32));
            float mnew  = fmaxf(m[qt], cmax);
            float alpha = __expf(m[qt] - mnew);
            m[qt] = mnew;
            float lsum = 0.0f;
            u16* prow = &Ps[(size_t)(w * 32 + qt * 16 + c) * KPAD];
            #pragma unroll
            for (int kt = 0; kt < 4; kt++) {
                float p0 = __expf(S[kt][0] - mnew);
                float p1 = __expf(S[kt][1] - mnew);
                float p2 = __expf(S[kt][2] - mnew);
                float p3 = __expf(S[kt][3] - mnew);
                lsum += (p0 + p1) + (p2 + p3);
                u32* pw = (u32*)&prow[kt * 16 + g * 4];
                pw[0] = pk2(p0, p1);
                pw[1] = pk2(p2, p3);
            }
            lsum += __shfl_xor(lsum, 16);
            lsum += __shfl_xor(lsum, 32);
            l[qt] = l[qt] * alpha + lsum;
            #pragma unroll
            for (int dt = 0; dt < 4; dt++) O[dt][qt] *= alpha;
        }

        #pragma unroll
        for (int kk = 0; kk < 2; kk++) {
            bf16x8 vfr[4];
            #pragma unroll
            for (int dt = 0; dt < 4; dt++)
                vfr[dt] = *(const bf16x8*)&Vt[(dt * 16 + c) * KPAD
                                              + (((4 * kk + g) ^ dt) << 3)];
            #pragma unroll
            for (int qt = 0; qt < 2; qt++) {
                bf16x8 pfr = *(const bf16x8*)&Ps[(size_t)(w * 32 + qt * 16 + c) * KPAD
                                                 + kk * 32 + g * 8];
                #pragma unroll
                for (int dt = 0; dt < 4; dt++)
                    O[dt][qt] = mfma16(vfr[dt], pfr, O[dt][qt]);
            }
        }
    }

    #pragma unroll
    for (int qt = 0; qt < 2; qt++) {
        float inv = 1.0f / fmaxf(l[qt], 1e-30f);
        float* orow = outg + (bhN + (size_t)qi[qt]) * DIM;
        #pragma unroll
        for (int dt = 0; dt < 4; dt++) {
            f32x4 o = O[dt][qt] * inv;
            *(f32x4*)(orow + dt * 16 + g * 4) = o;
        }
    }
}

// ---------------------------------------------------------------------------
extern "C" void kernel_launch(void* const* d_in, const int* in_sizes, int n_in,
                              void* d_out, int out_size, void* d_ws, size_t ws_size,
                              hipStream_t stream)
{
    const float* qg   = (const float*)d_in[0];
    const float* kg   = (const float*)d_in[1];
    const float* vg   = (const float*)d_in[2];
    const float* pg   = (const float*)d_in[3];
    const int*   samp = (const int*)d_in[4];
    float* outg = (float*)d_out;

    u16* qidx = (u16*)d_ws;                       // 512 KB
    u16* kidx = qidx + BHX * NSEQ;                // 512 KB
    u8*  bkt  = (u8*)(kidx + BHX * NSEQ);         // 512 KB

    hipLaunchKernelGGL(hash_kernel, dim3(8, BHX, 2), dim3(256), 0, stream,
                       qg, kg, pg, bkt);
    hipLaunchKernelGGL(sort_kernel, dim3(BHX, 2), dim3(256), 0, stream,
                       bkt, qidx, kidx);
    hipLaunchKernelGGL(attn_mfma, dim3(NBLK, BHX), dim3(512), 0, stream,
                       qg, kg, vg, qidx, kidx, samp, outg);
}

// Round 4
// 337.219 us; speedup vs baseline: 1.0239x; 1.0239x over previous
//
#include <hip/hip_runtime.h>

#define BHX   32      // B*H
#define NSEQ  8192
#define NMASK 8191
#define DIM   64
#define NPROJ 7
#define NBUCK 128
#define NBLK  32      // key blocks of 256
#define QBS   256
#define SSIZE 256
#define KPAD  72      // padded leading dim (bf16 units), rows 144 B (16B-aligned)
#define QSC   0.18033688f   // 0.125 * log2(e): softmax done in exp2 domain

typedef unsigned short u16;
typedef unsigned int   u32;
typedef unsigned char  u8;
typedef __attribute__((ext_vector_type(8))) short bf16x8;
typedef __attribute__((ext_vector_type(4))) float f32x4;

union B8U { u32 u[4]; bf16x8 v; };

__device__ __forceinline__ u16 f2bf(float f){
    u32 u = __float_as_uint(f);
    u32 r = u + 0x7fffu + ((u >> 16) & 1u);   // RNE
    return (u16)(r >> 16);
}
__device__ __forceinline__ u32 pk2(float a, float b){
    return (u32)f2bf(a) | ((u32)f2bf(b) << 16);
}
__device__ __forceinline__ f32x4 mfma16(bf16x8 a, bf16x8 b, f32x4 c){
    return __builtin_amdgcn_mfma_f32_16x16x32_bf16(a, b, c, 0, 0, 0);
}

// ---------------------------------------------------------------------------
// Kernel 1a: LSH hash. grid (8 slabs, BHX, 2 tensors), 256 thr, 4 rows/thr.
// ---------------------------------------------------------------------------
__global__ __launch_bounds__(256) void hash_kernel(
    const float* __restrict__ qg, const float* __restrict__ kg,
    const float* __restrict__ projg,
    u8* __restrict__ bkt)
{
    const int slab = blockIdx.x, bh = blockIdx.y, tz = blockIdx.z;
    const float* __restrict__ x = tz ? kg : qg;
    u8* __restrict__ ob = bkt + ((size_t)tz * BHX + bh) * NSEQ;

    __shared__ float projs[NPROJ][DIM];   // rows 256 B aligned -> float4 reads
    const int t = threadIdx.x;
    if (t < 112) {
        #pragma unroll
        for (int u = 0; u < 4; u++) {
            int e = t * 4 + u;
            projs[e % NPROJ][e / NPROJ] = projg[e];
        }
    }
    __syncthreads();

    const size_t bhN = (size_t)bh * NSEQ;
    #pragma unroll
    for (int j = 0; j < 4; j++) {
        int n = slab * 1024 + j * 256 + t;
        const float4* row = (const float4*)(x + (bhN + n) * DIM);
        float dot[NPROJ];
        #pragma unroll
        for (int r = 0; r < NPROJ; r++) dot[r] = 0.0f;
        #pragma unroll
        for (int c = 0; c < 16; c++) {
            float4 wv = row[c];
            #pragma unroll
            for (int r = 0; r < NPROJ; r++) {
                float4 p = *(const float4*)&projs[r][c * 4];
                dot[r] += wv.x * p.x;
                dot[r] += wv.y * p.y;
                dot[r] += wv.z * p.z;
                dot[r] += wv.w * p.w;
            }
        }
        int code = 0;
        #pragma unroll
        for (int r = 0; r < NPROJ; r++) code |= (dot[r] > 0.0f ? 1 : 0) << r;
        ob[n] = (u8)(code ^ (code >> 1));
    }
}

// ---------------------------------------------------------------------------
// Kernel 1b: stable counting sort per (tensor, head). grid (BHX, 2), 256 thr.
// v2: bucket scan via u32 pairs (conflict-free stride-129 rows, pipelined
// loads), base scan via 64-lane shuffle (was 128 dependent LDS reads @ t==0).
// ---------------------------------------------------------------------------
__global__ __launch_bounds__(256) void sort_kernel(
    const u8* __restrict__ bkt,
    u16* __restrict__ qidx, u16* __restrict__ kidx)
{
    const int bh = blockIdx.x, tz = blockIdx.y;
    const u8* __restrict__ ib = bkt + ((size_t)tz * BHX + bh) * NSEQ;
    u16* __restrict__ idx = (tz ? kidx : qidx) + (size_t)bh * NSEQ;

    __shared__ u8  lb[NSEQ];            // 8 KB
    __shared__ u16 hist[NBUCK][258];    // 66 KB, row = 129 dwords (odd stride)
    __shared__ int base[NBUCK];
    __shared__ int tot[NBUCK];

    const int t = threadIdx.x;
    {
        const uint4* src = (const uint4*)ib;
        uint4* dst = (uint4*)lb;
        dst[t] = src[t];
        dst[256 + t] = src[256 + t];
    }
    u32* hz = (u32*)&hist[0][0];
    for (int z = t; z < (NBUCK * 258) / 2; z += 256) hz[z] = 0u;
    __syncthreads();

    #pragma unroll 4
    for (int i = 0; i < 32; i++) hist[lb[t * 32 + i]][t]++;
    __syncthreads();

    // exclusive scan over 256 chunks per bucket: u32 pairs, independent loads
    if (t < NBUCK) {
        u32* hrow = (u32*)&hist[t][0];
        u32 run = 0;
        #pragma unroll 8
        for (int c = 0; c < 128; c++) {
            u32 v = hrow[c];
            u32 lo = v & 0xffffu, hi = v >> 16;
            hrow[c] = run | ((run + lo) << 16);
            run += lo + hi;
        }
        tot[t] = (int)run;
    }
    __syncthreads();

    // base: exclusive scan of tot[0..127] via one-wave shuffle scan
    if (t < 64) {
        int a = tot[2 * t], b = tot[2 * t + 1];
        int s = a + b;
        #pragma unroll
        for (int d = 1; d < 64; d <<= 1) {
            int v = __shfl_up(s, d);
            if (t >= d) s += v;
        }
        int excl = s - (a + b);
        base[2 * t]     = excl;
        base[2 * t + 1] = excl + a;
    }
    __syncthreads();

    #pragma unroll 4
    for (int i = 0; i < 32; i++) {
        int n = t * 32 + i;
        int b = lb[n];
        int pos = base[b] + hist[b][t];
        hist[b][t]++;
        idx[pos] = (u16)n;
    }
}

// ---------------------------------------------------------------------------
// Kernel 2: MFMA flash attention over 512 keys (256 block-diag + 256 sampled).
// grid (NBLK, BHX), 256 thr = 4 waves; wave owns 64 sorted queries.
// v3: NO P LDS round-trip. K (+bias) staged in permuted key order so the
// QK^T output registers, pk2-paired, ARE the PV B-fragment:
//   perm(m) = (m>>5)<<5 | ((m>>2)&3)<<3 | ((m>>4)&1)<<2 | (m&3)
//   (staged slot (kt, g*4+r) -> natural key (kt>>1)*32 + g*8 + (kt&1)*4 + r,
//    exactly the PV B-fragment element order)
// V staged in natural order as [d][key] via packed u32 pair-writes
// (conflict-free per half-wave: dword = d*36 + pair, pair = lane&31).
// Softmax in exp2 domain (QSC = 0.125*log2e folded into Q; LOG32 -> 5.0).
// cc loop pinned to unroll 1 (defensive: cap codegen size / compile time).
// ---------------------------------------------------------------------------
__global__ __launch_bounds__(256, 2) void attn_mfma(
    const float* __restrict__ qg, const float* __restrict__ kg,
    const float* __restrict__ vg,
    const u16* __restrict__ qidx, const u16* __restrict__ kidx,
    const int* __restrict__ samp,
    float* __restrict__ outg)
{
    __shared__ u16  Ks[64 * KPAD];        // [key][d], permuted key order, 9.2 KB
    __shared__ u16  Vt[64 * KPAD];        // [d][key], natural key order,  9.2 KB
    __shared__ float addv[64];            // bias, permuted key order

    const int qb = blockIdx.x, bh = blockIdx.y, t = threadIdx.x;
    const int w = t >> 6, lane = t & 63, c = lane & 15, g = lane >> 4;
    const size_t bhN = (size_t)bh * NSEQ;

    // ---- load my wave's 64 query rows as B-fragments (exp2 scale folded) ----
    int qi[4];
    bf16x8 qf[4][2];
    #pragma unroll
    for (int qt = 0; qt < 4; qt++) {
        qi[qt] = ((int)qidx[bhN + qb * QBS + w * 64 + qt * 16 + c]) & NMASK;
        const float* qr = qg + (bhN + (size_t)qi[qt]) * DIM;
        #pragma unroll
        for (int dk = 0; dk < 2; dk++) {
            int d0 = dk * 32 + g * 8;
            float4 xx = *(const float4*)(qr + d0);
            float4 yy = *(const float4*)(qr + d0 + 4);
            B8U f;
            f.u[0] = pk2(xx.x * QSC, xx.y * QSC);
            f.u[1] = pk2(xx.z * QSC, xx.w * QSC);
            f.u[2] = pk2(yy.x * QSC, yy.y * QSC);
            f.u[3] = pk2(yy.z * QSC, yy.w * QSC);
            qf[qt][dk] = f.v;
        }
    }

    f32x4 O[4][4];   // [dt][qt], C layout: row=d, col=query
    #pragma unroll
    for (int dt = 0; dt < 4; dt++)
        #pragma unroll
        for (int qt = 0; qt < 4; qt++) O[dt][qt] = (f32x4)0.0f;
    float m[4] = {-1e30f, -1e30f, -1e30f, -1e30f};
    float l[4] = {0.0f, 0.0f, 0.0f, 0.0f};

    // staging roles (each thread stages 1/4 K row AND 8 d of a V key-pair)
    const int ks_row = t >> 2, ks_q = t & 3;
    const int kp = ((ks_row >> 5) << 5) | (((ks_row >> 2) & 3) << 3)
                 | (((ks_row >> 4) & 1) << 2) | (ks_row & 3);    // perm
    const int vs_p = t & 31, vs_seg = (t >> 5) * 8;

    #pragma unroll 1
    for (int cc = 0; cc < 8; cc++) {
        __syncthreads();
        {
            // ---- K: permuted gather position kp -> Ks row ks_row ----
            int grow; float add;
            if (cc < 4) {
                grow = ((int)kidx[bhN + qb * QBS + cc * 64 + kp]) & NMASK;
                add  = 0.0f;
            } else {
                int sidx = samp[bh * SSIZE + (cc - 4) * 64 + kp] & NMASK;
                grow = ((int)kidx[bhN + sidx]) & NMASK;
                add  = ((sidx >> 8) == qb) ? -1e30f : 5.0f;   // log2(32)
            }
            const float4* kr = (const float4*)(kg + (bhN + (size_t)grow) * DIM + ks_q * 16);
            float4 ak = kr[0], bk = kr[1], ck = kr[2], ek = kr[3];
            u32* dst = (u32*)&Ks[ks_row * KPAD + ks_q * 16];
            dst[0] = pk2(ak.x, ak.y); dst[1] = pk2(ak.z, ak.w);
            dst[2] = pk2(bk.x, bk.y); dst[3] = pk2(bk.z, bk.w);
            dst[4] = pk2(ck.x, ck.y); dst[5] = pk2(ck.z, ck.w);
            dst[6] = pk2(ek.x, ek.y); dst[7] = pk2(ek.z, ek.w);
            if (ks_q == 0) addv[ks_row] = add;

            // ---- V: natural order, keys 2*vs_p, 2*vs_p+1, d seg of 8 ----
            int n0 = 2 * vs_p, n1 = n0 + 1;
            int g0, g1;
            if (cc < 4) {
                g0 = ((int)kidx[bhN + qb * QBS + cc * 64 + n0]) & NMASK;
                g1 = ((int)kidx[bhN + qb * QBS + cc * 64 + n1]) & NMASK;
            } else {
                int s0 = samp[bh * SSIZE + (cc - 4) * 64 + n0] & NMASK;
                int s1 = samp[bh * SSIZE + (cc - 4) * 64 + n1] & NMASK;
                g0 = ((int)kidx[bhN + s0]) & NMASK;
                g1 = ((int)kidx[bhN + s1]) & NMASK;
            }
            const float4* v0 = (const float4*)(vg + (bhN + (size_t)g0) * DIM + vs_seg);
            const float4* v1 = (const float4*)(vg + (bhN + (size_t)g1) * DIM + vs_seg);
            float4 a0 = v0[0], b0 = v0[1];
            float4 a1 = v1[0], b1 = v1[1];
            float va[8] = {a0.x, a0.y, a0.z, a0.w, b0.x, b0.y, b0.z, b0.w};
            float vb[8] = {a1.x, a1.y, a1.z, a1.w, b1.x, b1.y, b1.z, b1.w};
            u32* vtu = (u32*)Vt;
            #pragma unroll
            for (int i = 0; i < 8; i++)
                vtu[(vs_seg + i) * (KPAD / 2) + vs_p] = pk2(va[i], vb[i]);
        }
        __syncthreads();

        f32x4 addn[4];
        #pragma unroll
        for (int kt = 0; kt < 4; kt++)
            addn[kt] = *(const f32x4*)&addv[kt * 16 + g * 4];

        bf16x8 ka[4][2];
        #pragma unroll
        for (int kt = 0; kt < 4; kt++)
            #pragma unroll
            for (int dd = 0; dd < 2; dd++)
                ka[kt][dd] = *(const bf16x8*)&Ks[(kt * 16 + c) * KPAD + dd * 32 + g * 8];

        bf16x8 vfr[2][4];
        #pragma unroll
        for (int kk = 0; kk < 2; kk++)
            #pragma unroll
            for (int dt = 0; dt < 4; dt++)
                vfr[kk][dt] = *(const bf16x8*)&Vt[(dt * 16 + c) * KPAD + kk * 32 + g * 8];

        #pragma unroll
        for (int qt = 0; qt < 4; qt++) {
            f32x4 S[4];
            #pragma unroll
            for (int kt = 0; kt < 4; kt++) {
                S[kt] = (f32x4)0.0f;
                S[kt] = mfma16(ka[kt][0], qf[qt][0], S[kt]);
                S[kt] = mfma16(ka[kt][1], qf[qt][1], S[kt]);
                S[kt] += addn[kt];
            }
            float cmax = -1e30f;
            #pragma unroll
            for (int kt = 0; kt < 4; kt++)
                #pragma unroll
                for (int r = 0; r < 4; r++)
                    cmax = fmaxf(cmax, S[kt][r]);
            cmax = fmaxf(cmax, __shfl_xor(cmax, 16));
            cmax = fmaxf(cmax, __shfl_xor(cmax, 32));
            float mnew  = fmaxf(m[qt], cmax);
            float alpha = __builtin_exp2f(m[qt] - mnew);
            m[qt] = mnew;
            float lsum = 0.0f;
            u32 pp[4][2];
            #pragma unroll
            for (int kt = 0; kt < 4; kt++) {
                float p0 = __builtin_exp2f(S[kt][0] - mnew);
                float p1 = __builtin_exp2f(S[kt][1] - mnew);
                float p2 = __builtin_exp2f(S[kt][2] - mnew);
                float p3 = __builtin_exp2f(S[kt][3] - mnew);
                lsum += (p0 + p1) + (p2 + p3);
                pp[kt][0] = pk2(p0, p1);
                pp[kt][1] = pk2(p2, p3);
            }
            lsum += __shfl_xor(lsum, 16);
            lsum += __shfl_xor(lsum, 32);
            l[qt] = l[qt] * alpha + lsum;
            #pragma unroll
            for (int dt = 0; dt < 4; dt++) O[dt][qt] *= alpha;

            // PV: pk2 pairs ARE the B-fragment (key perm arranged it)
            #pragma unroll
            for (int kk = 0; kk < 2; kk++) {
                B8U pf;
                pf.u[0] = pp[2 * kk][0];
                pf.u[1] = pp[2 * kk][1];
                pf.u[2] = pp[2 * kk + 1][0];
                pf.u[3] = pp[2 * kk + 1][1];
                #pragma unroll
                for (int dt = 0; dt < 4; dt++)
                    O[dt][qt] = mfma16(vfr[kk][dt], pf.v, O[dt][qt]);
            }
        }
    }

    #pragma unroll
    for (int qt = 0; qt < 4; qt++) {
        float inv = 1.0f / fmaxf(l[qt], 1e-30f);
        float* orow = outg + (bhN + (size_t)qi[qt]) * DIM;
        #pragma unroll
        for (int dt = 0; dt < 4; dt++) {
            f32x4 o = O[dt][qt] * inv;
            *(f32x4*)(orow + dt * 16 + g * 4) = o;
        }
    }
}

// ---------------------------------------------------------------------------
extern "C" void kernel_launch(void* const* d_in, const int* in_sizes, int n_in,
                              void* d_out, int out_size, void* d_ws, size_t ws_size,
                              hipStream_t stream)
{
    const float* qg   = (const float*)d_in[0];
    const float* kg   = (const float*)d_in[1];
    const float* vg   = (const float*)d_in[2];
    const float* pg   = (const float*)d_in[3];
    const int*   samp = (const int*)d_in[4];
    float* outg = (float*)d_out;

    u16* qidx = (u16*)d_ws;                       // 512 KB
    u16* kidx = qidx + BHX * NSEQ;                // 512 KB
    u8*  bkt  = (u8*)(kidx + BHX * NSEQ);         // 512 KB

    hipLaunchKernelGGL(hash_kernel, dim3(8, BHX, 2), dim3(256), 0, stream,
                       qg, kg, pg, bkt);
    hipLaunchKernelGGL(sort_kernel, dim3(BHX, 2), dim3(256), 0, stream,
                       bkt, qidx, kidx);
    hipLaunchKernelGGL(attn_mfma, dim3(NBLK, BHX), dim3(256), 0, stream,
                       qg, kg, vg, qidx, kidx, samp, outg);
}

// Round 5
// 324.067 us; speedup vs baseline: 1.0654x; 1.0406x over previous
//
#include <hip/hip_runtime.h>

#define BHX   32      // B*H
#define NSEQ  8192
#define NMASK 8191
#define DIM   64
#define NPROJ 7
#define NBUCK 128
#define NBLK  32      // key blocks of 256
#define QBS   256
#define SSIZE 256
#define KPAD  72      // padded leading dim (bf16 units), rows 144 B (16B-aligned)
#define QSC   0.18033688f   // 0.125 * log2(e): softmax done in exp2 domain

typedef unsigned short u16;
typedef unsigned int   u32;
typedef unsigned char  u8;
typedef __attribute__((ext_vector_type(8))) short bf16x8;
typedef __attribute__((ext_vector_type(4))) float f32x4;

union B8U { u32 u[4]; bf16x8 v; };

// one-instruction packed f32->bf16 RNE (v_cvt_pk_bf16_f32): replaces ~10-op
// manual RNE pair packing. D[15:0]=bf16(a), D[31:16]=bf16(b).
__device__ __forceinline__ u32 cpk(float a, float b){
    u32 r;
    asm("v_cvt_pk_bf16_f32 %0, %1, %2" : "=v"(r) : "v"(a), "v"(b));
    return r;
}
__device__ __forceinline__ f32x4 mfma16(bf16x8 a, bf16x8 b, f32x4 c){
    return __builtin_amdgcn_mfma_f32_16x16x32_bf16(a, b, c, 0, 0, 0);
}

// ---------------------------------------------------------------------------
// Kernel 1a: LSH hash. grid (8 slabs, BHX, 2 tensors), 256 thr, 4 rows/thr.
// ---------------------------------------------------------------------------
__global__ __launch_bounds__(256) void hash_kernel(
    const float* __restrict__ qg, const float* __restrict__ kg,
    const float* __restrict__ projg,
    u8* __restrict__ bkt)
{
    const int slab = blockIdx.x, bh = blockIdx.y, tz = blockIdx.z;
    const float* __restrict__ x = tz ? kg : qg;
    u8* __restrict__ ob = bkt + ((size_t)tz * BHX + bh) * NSEQ;

    __shared__ float projs[NPROJ][DIM];   // rows 256 B aligned -> float4 reads
    const int t = threadIdx.x;
    if (t < 112) {
        #pragma unroll
        for (int u = 0; u < 4; u++) {
            int e = t * 4 + u;
            projs[e % NPROJ][e / NPROJ] = projg[e];
        }
    }
    __syncthreads();

    const size_t bhN = (size_t)bh * NSEQ;
    #pragma unroll
    for (int j = 0; j < 4; j++) {
        int n = slab * 1024 + j * 256 + t;
        const float4* row = (const float4*)(x + (bhN + n) * DIM);
        float dot[NPROJ];
        #pragma unroll
        for (int r = 0; r < NPROJ; r++) dot[r] = 0.0f;
        #pragma unroll
        for (int c = 0; c < 16; c++) {
            float4 wv = row[c];
            #pragma unroll
            for (int r = 0; r < NPROJ; r++) {
                float4 p = *(const float4*)&projs[r][c * 4];
                dot[r] += wv.x * p.x;
                dot[r] += wv.y * p.y;
                dot[r] += wv.z * p.z;
                dot[r] += wv.w * p.w;
            }
        }
        int code = 0;
        #pragma unroll
        for (int r = 0; r < NPROJ; r++) code |= (dot[r] > 0.0f ? 1 : 0) << r;
        ob[n] = (u8)(code ^ (code >> 1));
    }
}

// ---------------------------------------------------------------------------
// Kernel 1b: stable counting sort per (tensor, head). grid (BHX, 2), 256 thr.
// ---------------------------------------------------------------------------
__global__ __launch_bounds__(256) void sort_kernel(
    const u8* __restrict__ bkt,
    u16* __restrict__ qidx, u16* __restrict__ kidx)
{
    const int bh = blockIdx.x, tz = blockIdx.y;
    const u8* __restrict__ ib = bkt + ((size_t)tz * BHX + bh) * NSEQ;
    u16* __restrict__ idx = (tz ? kidx : qidx) + (size_t)bh * NSEQ;

    __shared__ u8  lb[NSEQ];            // 8 KB
    __shared__ u16 hist[NBUCK][258];    // 66 KB, row = 129 dwords (odd stride)
    __shared__ int base[NBUCK];
    __shared__ int tot[NBUCK];

    const int t = threadIdx.x;
    {
        const uint4* src = (const uint4*)ib;
        uint4* dst = (uint4*)lb;
        dst[t] = src[t];
        dst[256 + t] = src[256 + t];
    }
    u32* hz = (u32*)&hist[0][0];
    for (int z = t; z < (NBUCK * 258) / 2; z += 256) hz[z] = 0u;
    __syncthreads();

    #pragma unroll 4
    for (int i = 0; i < 32; i++) hist[lb[t * 32 + i]][t]++;
    __syncthreads();

    // exclusive scan over 256 chunks per bucket: u32 pairs, independent loads
    if (t < NBUCK) {
        u32* hrow = (u32*)&hist[t][0];
        u32 run = 0;
        #pragma unroll 8
        for (int c = 0; c < 128; c++) {
            u32 v = hrow[c];
            u32 lo = v & 0xffffu, hi = v >> 16;
            hrow[c] = run | ((run + lo) << 16);
            run += lo + hi;
        }
        tot[t] = (int)run;
    }
    __syncthreads();

    // base: exclusive scan of tot[0..127] via one-wave shuffle scan
    if (t < 64) {
        int a = tot[2 * t], b = tot[2 * t + 1];
        int s = a + b;
        #pragma unroll
        for (int d = 1; d < 64; d <<= 1) {
            int v = __shfl_up(s, d);
            if (t >= d) s += v;
        }
        int excl = s - (a + b);
        base[2 * t]     = excl;
        base[2 * t + 1] = excl + a;
    }
    __syncthreads();

    #pragma unroll 4
    for (int i = 0; i < 32; i++) {
        int n = t * 32 + i;
        int b = lb[n];
        int pos = base[b] + hist[b][t];
        hist[b][t]++;
        idx[pos] = (u16)n;
    }
}

// ---------------------------------------------------------------------------
// Kernel 2: MFMA flash attention over 512 keys (256 block-diag + 256 sampled).
// grid (NBLK, BHX), 256 thr = 4 waves; wave owns 64 sorted queries.
// v4 on top of v3's register-P structure:
//  - v_cvt_pk_bf16_f32 (1 instr) replaces ~10-op manual RNE pack everywhere
//  - T14 async-stage: chunk cc+1's gathered K/V rows load into registers
//    during chunk cc's compute; converted+written to LDS after the barrier
//  - bias folded into QK^T MFMA C-in (no S += addn pass)
//  - T13 defer-rescale: skip alpha path when no query's max grew
// ---------------------------------------------------------------------------
__global__ __launch_bounds__(256, 2) void attn_mfma(
    const float* __restrict__ qg, const float* __restrict__ kg,
    const float* __restrict__ vg,
    const u16* __restrict__ qidx, const u16* __restrict__ kidx,
    const int* __restrict__ samp,
    float* __restrict__ outg)
{
    __shared__ u16  Ks[64 * KPAD];        // [key][d], permuted key order, 9.2 KB
    __shared__ u16  Vt[64 * KPAD];        // [d][key], natural key order,  9.2 KB
    __shared__ float addv[64];            // bias, permuted key order

    const int qb = blockIdx.x, bh = blockIdx.y, t = threadIdx.x;
    const int w = t >> 6, lane = t & 63, c = lane & 15, g = lane >> 4;
    const size_t bhN = (size_t)bh * NSEQ;

    // ---- load my wave's 64 query rows as B-fragments (exp2 scale folded) ----
    int qi[4];
    bf16x8 qf[4][2];
    #pragma unroll
    for (int qt = 0; qt < 4; qt++) {
        qi[qt] = ((int)qidx[bhN + qb * QBS + w * 64 + qt * 16 + c]) & NMASK;
        const float* qr = qg + (bhN + (size_t)qi[qt]) * DIM;
        #pragma unroll
        for (int dk = 0; dk < 2; dk++) {
            int d0 = dk * 32 + g * 8;
            float4 xx = *(const float4*)(qr + d0);
            float4 yy = *(const float4*)(qr + d0 + 4);
            B8U f;
            f.u[0] = cpk(xx.x * QSC, xx.y * QSC);
            f.u[1] = cpk(xx.z * QSC, xx.w * QSC);
            f.u[2] = cpk(yy.x * QSC, yy.y * QSC);
            f.u[3] = cpk(yy.z * QSC, yy.w * QSC);
            qf[qt][dk] = f.v;
        }
    }

    f32x4 O[4][4];   // [dt][qt], C layout: row=d, col=query
    #pragma unroll
    for (int dt = 0; dt < 4; dt++)
        #pragma unroll
        for (int qt = 0; qt < 4; qt++) O[dt][qt] = (f32x4)0.0f;
    float m[4] = {-1e30f, -1e30f, -1e30f, -1e30f};
    float l[4] = {0.0f, 0.0f, 0.0f, 0.0f};

    // staging roles (each thread stages 1/4 K row AND 8 d of a V key-pair)
    const int ks_row = t >> 2, ks_q = t & 3;
    const int kp = ((ks_row >> 5) << 5) | (((ks_row >> 2) & 3) << 3)
                 | (((ks_row >> 4) & 1) << 2) | (ks_row & 3);    // perm
    const int vs_p = t & 31, vs_seg = (t >> 5) * 8;

    // prefetch registers (live across compute; converted only at write time)
    float4 kA, kB, kC, kD;     // K quarter row (16 f32)
    float4 vA, vB, vC, vD;     // V 8-d segs of two keys (16 f32)
    float  padd;

    auto prefetch = [&](int cc) {
        int grow;
        if (cc < 4) {
            grow = ((int)kidx[bhN + qb * QBS + cc * 64 + kp]) & NMASK;
            padd = 0.0f;
        } else {
            int sidx = samp[bh * SSIZE + (cc - 4) * 64 + kp] & NMASK;
            grow = ((int)kidx[bhN + sidx]) & NMASK;
            padd = ((sidx >> 8) == qb) ? -1e30f : 5.0f;   // log2(32)
        }
        const float4* kr = (const float4*)(kg + (bhN + (size_t)grow) * DIM + ks_q * 16);
        kA = kr[0]; kB = kr[1]; kC = kr[2]; kD = kr[3];
        int n0 = 2 * vs_p, n1 = n0 + 1, g0, g1;
        if (cc < 4) {
            g0 = ((int)kidx[bhN + qb * QBS + cc * 64 + n0]) & NMASK;
            g1 = ((int)kidx[bhN + qb * QBS + cc * 64 + n1]) & NMASK;
        } else {
            int s0 = samp[bh * SSIZE + (cc - 4) * 64 + n0] & NMASK;
            int s1 = samp[bh * SSIZE + (cc - 4) * 64 + n1] & NMASK;
            g0 = ((int)kidx[bhN + s0]) & NMASK;
            g1 = ((int)kidx[bhN + s1]) & NMASK;
        }
        const float4* v0 = (const float4*)(vg + (bhN + (size_t)g0) * DIM + vs_seg);
        const float4* v1 = (const float4*)(vg + (bhN + (size_t)g1) * DIM + vs_seg);
        vA = v0[0]; vB = v0[1]; vC = v1[0]; vD = v1[1];
    };

    prefetch(0);

    #pragma unroll 1
    for (int cc = 0; cc < 8; cc++) {
        __syncthreads();   // prior chunk's LDS consumers done
        {
            // ---- write prefetched K (permuted order) + V^T to LDS ----
            u32* dst = (u32*)&Ks[ks_row * KPAD + ks_q * 16];
            dst[0] = cpk(kA.x, kA.y); dst[1] = cpk(kA.z, kA.w);
            dst[2] = cpk(kB.x, kB.y); dst[3] = cpk(kB.z, kB.w);
            dst[4] = cpk(kC.x, kC.y); dst[5] = cpk(kC.z, kC.w);
            dst[6] = cpk(kD.x, kD.y); dst[7] = cpk(kD.z, kD.w);
            if (ks_q == 0) addv[ks_row] = padd;
            float va[8] = {vA.x, vA.y, vA.z, vA.w, vB.x, vB.y, vB.z, vB.w};
            float vb[8] = {vC.x, vC.y, vC.z, vC.w, vD.x, vD.y, vD.z, vD.w};
            u32* vtu = (u32*)Vt;
            #pragma unroll
            for (int i = 0; i < 8; i++)
                vtu[(vs_seg + i) * (KPAD / 2) + vs_p] = cpk(va[i], vb[i]);
        }
        __syncthreads();

        if (cc < 7) prefetch(cc + 1);   // loads in flight under compute below

        f32x4 addn[4];
        #pragma unroll
        for (int kt = 0; kt < 4; kt++)
            addn[kt] = *(const f32x4*)&addv[kt * 16 + g * 4];

        bf16x8 ka[4][2];
        #pragma unroll
        for (int kt = 0; kt < 4; kt++)
            #pragma unroll
            for (int dd = 0; dd < 2; dd++)
                ka[kt][dd] = *(const bf16x8*)&Ks[(kt * 16 + c) * KPAD + dd * 32 + g * 8];

        bf16x8 vfr[2][4];
        #pragma unroll
        for (int kk = 0; kk < 2; kk++)
            #pragma unroll
            for (int dt = 0; dt < 4; dt++)
                vfr[kk][dt] = *(const bf16x8*)&Vt[(dt * 16 + c) * KPAD + kk * 32 + g * 8];

        #pragma unroll
        for (int qt = 0; qt < 4; qt++) {
            f32x4 S[4];
            #pragma unroll
            for (int kt = 0; kt < 4; kt++) {
                S[kt] = mfma16(ka[kt][0], qf[qt][0], addn[kt]);  // bias as C-in
                S[kt] = mfma16(ka[kt][1], qf[qt][1], S[kt]);
            }
            float cmax = -1e30f;
            #pragma unroll
            for (int kt = 0; kt < 4; kt++)
                #pragma unroll
                for (int r = 0; r < 4; r++)
                    cmax = fmaxf(cmax, S[kt][r]);
            cmax = fmaxf(cmax, __shfl_xor(cmax, 16));
            cmax = fmaxf(cmax, __shfl_xor(cmax, 32));
            if (__any(cmax > m[qt])) {       // T13: rescale only when needed
                float mnew  = fmaxf(m[qt], cmax);
                float alpha = __builtin_exp2f(m[qt] - mnew);
                m[qt] = mnew;
                l[qt] *= alpha;
                #pragma unroll
                for (int dt = 0; dt < 4; dt++) O[dt][qt] *= alpha;
            }
            const float mq = m[qt];
            float lsum = 0.0f;
            u32 pp[4][2];
            #pragma unroll
            for (int kt = 0; kt < 4; kt++) {
                float p0 = __builtin_exp2f(S[kt][0] - mq);
                float p1 = __builtin_exp2f(S[kt][1] - mq);
                float p2 = __builtin_exp2f(S[kt][2] - mq);
                float p3 = __builtin_exp2f(S[kt][3] - mq);
                lsum += (p0 + p1) + (p2 + p3);
                pp[kt][0] = cpk(p0, p1);
                pp[kt][1] = cpk(p2, p3);
            }
            lsum += __shfl_xor(lsum, 16);
            lsum += __shfl_xor(lsum, 32);
            l[qt] += lsum;

            // PV: cvt_pk pairs ARE the B-fragment (key perm arranged it)
            #pragma unroll
            for (int kk = 0; kk < 2; kk++) {
                B8U pf;
                pf.u[0] = pp[2 * kk][0];
                pf.u[1] = pp[2 * kk][1];
                pf.u[2] = pp[2 * kk + 1][0];
                pf.u[3] = pp[2 * kk + 1][1];
                #pragma unroll
                for (int dt = 0; dt < 4; dt++)
                    O[dt][qt] = mfma16(vfr[kk][dt], pf.v, O[dt][qt]);
            }
        }
    }

    #pragma unroll
    for (int qt = 0; qt < 4; qt++) {
        float inv = 1.0f / fmaxf(l[qt], 1e-30f);
        float* orow = outg + (bhN + (size_t)qi[qt]) * DIM;
        #pragma unroll
        for (int dt = 0; dt < 4; dt++) {
            f32x4 o = O[dt][qt] * inv;
            *(f32x4*)(orow + dt * 16 + g * 4) = o;
        }
    }
}

// ---------------------------------------------------------------------------
extern "C" void kernel_launch(void* const* d_in, const int* in_sizes, int n_in,
                              void* d_out, int out_size, void* d_ws, size_t ws_size,
                              hipStream_t stream)
{
    const float* qg   = (const float*)d_in[0];
    const float* kg   = (const float*)d_in[1];
    const float* vg   = (const float*)d_in[2];
    const float* pg   = (const float*)d_in[3];
    const int*   samp = (const int*)d_in[4];
    float* outg = (float*)d_out;

    u16* qidx = (u16*)d_ws;                       // 512 KB
    u16* kidx = qidx + BHX * NSEQ;                // 512 KB
    u8*  bkt  = (u8*)(kidx + BHX * NSEQ);         // 512 KB

    hipLaunchKernelGGL(hash_kernel, dim3(8, BHX, 2), dim3(256), 0, stream,
                       qg, kg, pg, bkt);
    hipLaunchKernelGGL(sort_kernel, dim3(BHX, 2), dim3(256), 0, stream,
                       bkt, qidx, kidx);
    hipLaunchKernelGGL(attn_mfma, dim3(NBLK, BHX), dim3(256), 0, stream,
                       qg, kg, vg, qidx, kidx, samp, outg);
}